// Round 1
// baseline (181.888 us; speedup 1.0000x reference)
//
#include <hip/hip_runtime.h>
#include <hip/hip_bf16.h>

typedef unsigned short u16;
typedef unsigned int   u32;

typedef __bf16 bf16x8 __attribute__((ext_vector_type(8)));
typedef float  f32x4  __attribute__((ext_vector_type(4)));

__device__ __forceinline__ u16 f2b(float f) {
    __hip_bfloat16 h = __float2bfloat16(f);
    u16 u; __builtin_memcpy(&u, &h, 2); return u;
}
__device__ __forceinline__ float blo(u32 u) { return __uint_as_float(u << 16); }
__device__ __forceinline__ float bhi(u32 u) { return __uint_as_float(u & 0xffff0000u); }

// ---------------------------------------------------------------------------
// prep (input padding eliminated — conv stages fp32 directly):
//  section B (blocks [0,1152)):    weights -> MFMA B-fragment order
//       BF[(((p*4+kk)*4+q)*256 + n)*8 + j] = bf16(w[(p*128+kk*32+q*8+j)*256+n])
//  section C (blocks [1152,1200)): zero s0,s2,s3 (12288 floats)
// ---------------------------------------------------------------------------
__global__ void k_prep(const float* __restrict__ wk,
                       u16* __restrict__ BF, float* __restrict__ stats) {
    int bx = blockIdx.x, tid = threadIdx.x;
    if (bx < 1152) {
        int t = bx * 256 + tid;                   // 294912 total, exact
        int j  = t & 7;
        int n  = (t >> 3) & 255;
        int q  = (t >> 11) & 3;
        int kk = (t >> 13) & 3;
        int p  = t >> 15;
        BF[t] = f2b(wk[(p * 128 + kk * 32 + q * 8 + j) * 256 + n]);
    } else {
        stats[(bx - 1152) * 256 + tid] = 0.f;     // 12288 floats
    }
}

// ---------------------------------------------------------------------------
// conv: implicit GEMM. Block = one image row: M=64, N=256, K=1152. 4 waves,
// wave tile 64x64 (4x4 16x16x32 bf16 MFMA).
// R13 changes vs R12 baseline (which was 2 waves/SIMD, MfmaUtil 25%):
//  - B ping-pong at 4-fragment (per-kk) granularity: B0[4]+B1[4] = 32 VGPR
//    (was 64) -> unified regs ~192 -> ~150, targeting 3 waves/SIMD.
//  - __launch_bounds__(256,3): allocator budget 512/3 ~ 168 unified regs.
//  - STAGE made branchless (clamped address + x0 masking) so the unrolled
//    loop issues all 14 dwordx4 loads before the first wait (was: divergent
//    branch per chunk -> serialized issue/wait/cvt chains).
// Swizzled LDS layout [pr][wp][cs^(wp&7)] unchanged; barrier-free K-loop
// unchanged. Epilogue: +bias, relu, store x bf16, atomic-accumulate s0.
// ---------------------------------------------------------------------------
__launch_bounds__(256, 3)
__global__ void k_conv(const float* __restrict__ in, const u16* __restrict__ BF,
                       const float* __restrict__ bias,
                       u16* __restrict__ X, float* __restrict__ s0) {
    __shared__ u16 ldsA[12672];                   // 3*66*8 chunks = 25344 B
    const int t = threadIdx.x;
    const int lane = t & 63, wid = t >> 6;        // 4 waves
    const int q = lane >> 4, l15 = lane & 15;
    const int bb = blockIdx.x >> 6;               // batch
    const int h  = blockIdx.x & 63;               // output row
    const int wn0 = wid << 6;                     // wave's n-offset (64 each)

    // stage channel-half S from fp32 input; LDS[pr][wp][cs] = in[.., cs^(wp&7)]
    // branchless: OOB lanes load from a clamped valid address, result zeroed.
#define STAGE(S) { \
    const int sb0 = wid * 396; \
    _Pragma("unroll") for (int i = 0; i < 7; ++i) { \
        int slot = sb0 + i * 64 + lane; \
        if (i < 6 || lane < 12) { \
            int pr = slot / 528; int rem = slot - pr * 528; \
            int wp = rem >> 3, cs = rem & 7; \
            int gc = (S) * 8 + (cs ^ (wp & 7)); \
            int y = h + pr - 1, x = wp - 1; \
            int inb = ((unsigned)y < 64u) & ((unsigned)x < 64u); \
            int ys = inb ? y : 0, xs = inb ? x : 0; \
            const float4* s4 = (const float4*)(in + \
                (((bb * 64 + ys) * 64 + xs) * 128 + gc * 8)); \
            float4 f0 = s4[0], f1 = s4[1]; \
            float zf = inb ? 1.f : 0.f; \
            u16 ov[8]; \
            ov[0]=f2b(f0.x*zf); ov[1]=f2b(f0.y*zf); ov[2]=f2b(f0.z*zf); ov[3]=f2b(f0.w*zf); \
            ov[4]=f2b(f1.x*zf); ov[5]=f2b(f1.y*zf); ov[6]=f2b(f1.z*zf); ov[7]=f2b(f1.w*zf); \
            uint4 wv; __builtin_memcpy(&wv, ov, 16); \
            *(uint4*)((char*)ldsA + slot * 16) = wv; \
        } \
    } }

    // load one 4-fragment B group: (pos P, channel-half S, k-sub KK)
#define LOADB4(B, P, S, KK) { \
    _Pragma("unroll") for (int ni = 0; ni < 4; ++ni) \
        B[ni] = *(const bf16x8*)(BFl + (P) * 32768 + \
                                 ((S) * 2 + (KK)) * 8192 + ni * 128); }

    // one 16-MFMA compute step for (DH, DW, KK) using B group B
#define COMP4(B, DH, DW, KK) { \
    bf16x8 af[4]; \
    _Pragma("unroll") for (int mi = 0; mi < 4; ++mi) { \
        int wp = mi * 16 + l15 + (DW); \
        int swz = ((KK) * 4 + q) ^ (wp & 7); \
        af[mi] = *(const bf16x8*)((const char*)ldsA + \
            (((DH) * 528 + wp * 8 + swz) << 4)); \
    } \
    _Pragma("unroll") for (int mi = 0; mi < 4; ++mi) \
    _Pragma("unroll") for (int ni = 0; ni < 4; ++ni) \
        acc[mi][ni] = __builtin_amdgcn_mfma_f32_16x16x32_bf16( \
            af[mi], B[ni], acc[mi][ni], 0, 0, 0); }

    // 18 load-steps / 18 compute-steps per half, register ping-pong, no
    // barriers inside the half. (P,KK) walked in order P-major, KK inner.
#define HALF(S) { \
    LOADB4(B0, 0, S, 0); \
    LOADB4(B1, 0, S, 1); COMP4(B0, 0, 0, 0); \
    LOADB4(B0, 1, S, 0); COMP4(B1, 0, 0, 1); \
    LOADB4(B1, 1, S, 1); COMP4(B0, 0, 1, 0); \
    LOADB4(B0, 2, S, 0); COMP4(B1, 0, 1, 1); \
    LOADB4(B1, 2, S, 1); COMP4(B0, 0, 2, 0); \
    LOADB4(B0, 3, S, 0); COMP4(B1, 0, 2, 1); \
    LOADB4(B1, 3, S, 1); COMP4(B0, 1, 0, 0); \
    LOADB4(B0, 4, S, 0); COMP4(B1, 1, 0, 1); \
    LOADB4(B1, 4, S, 1); COMP4(B0, 1, 1, 0); \
    LOADB4(B0, 5, S, 0); COMP4(B1, 1, 1, 1); \
    LOADB4(B1, 5, S, 1); COMP4(B0, 1, 2, 0); \
    LOADB4(B0, 6, S, 0); COMP4(B1, 1, 2, 1); \
    LOADB4(B1, 6, S, 1); COMP4(B0, 2, 0, 0); \
    LOADB4(B0, 7, S, 0); COMP4(B1, 2, 0, 1); \
    LOADB4(B1, 7, S, 1); COMP4(B0, 2, 1, 0); \
    LOADB4(B0, 8, S, 0); COMP4(B1, 2, 1, 1); \
    LOADB4(B1, 8, S, 1); COMP4(B0, 2, 2, 0); \
                         COMP4(B1, 2, 2, 1); }

    const u16* BFl = BF + (q * 2048 + (wn0 + l15) * 8);

    f32x4 zero = {0.f, 0.f, 0.f, 0.f};
    f32x4 acc[4][4];
    #pragma unroll
    for (int mi = 0; mi < 4; ++mi)
        #pragma unroll
        for (int ni = 0; ni < 4; ++ni) acc[mi][ni] = zero;

    bf16x8 B0[4], B1[4];

    // ---- channel half 0 ----
    STAGE(0);
    __syncthreads();
    HALF(0);
    __syncthreads();                              // all half-0 LDS reads done

    // ---- channel half 1 ----
    STAGE(1);
    __syncthreads();
    HALF(1);

    // epilogue: bias + relu, store bf16 x, column sums -> s0
    float bv[4];
    #pragma unroll
    for (int ni = 0; ni < 4; ++ni) bv[ni] = bias[wn0 + ni * 16 + l15];
    float colsum[4] = {0.f, 0.f, 0.f, 0.f};
    u16* xrow = X + (((bb << 12) + (h << 6) + q * 4) * 256) + wn0 + l15;
    #pragma unroll
    for (int mi = 0; mi < 4; ++mi) {
        #pragma unroll
        for (int rr = 0; rr < 4; ++rr) {
            u16* xp = xrow + (mi * 16 + rr) * 256;
            #pragma unroll
            for (int ni = 0; ni < 4; ++ni) {
                float v = acc[mi][ni][rr] + bv[ni];
                v = v > 0.f ? v : 0.f;
                xp[ni * 16] = f2b(v);
                colsum[ni] += v;
            }
        }
    }
    #pragma unroll
    for (int ni = 0; ni < 4; ++ni) {
        float c = colsum[ni];
        c += __shfl_xor(c, 16);
        c += __shfl_xor(c, 32);
        if (lane < 16) atomicAdd(&s0[bb * 256 + wn0 + ni * 16 + l15], c);
    }
#undef STAGE
#undef LOADB4
#undef COMP4
#undef HALF
}

// ---------------------------------------------------------------------------
// routing pass v3 (R9/R11-measured best): 64 positions/block, grid 64x16 =
// 1024 blocks (4 blocks/CU -> enough TLP; 256-pos/1-block-per-CU variant
// regressed 40us in R12). vsum = l2n(Sa) (+ l2n(Sb)) register-cached -> ONE
// dot per position. Stride-17 LDS, 8 outstanding X-loads, shfl n-reduce.
// thread (c=t&15, nl=t>>4). b-logits bounded -> no softmax max pass.
// ---------------------------------------------------------------------------
__launch_bounds__(256, 4)
__global__ void k_pass(const u16* __restrict__ X, const float* __restrict__ Sa,
                       const float* __restrict__ Sb, float* __restrict__ Sout,
                       int use2) {
    __shared__ float vs[272];                     // [cap*17 + d]
    __shared__ float red[4 * 272];                // [wave][c*17 + d]
    const int t = threadIdx.x, b = blockIdx.y, chunk = blockIdx.x;
    const int c = t & 15, nl = t >> 4;
    const int lane = t & 63, wid = t >> 6;
    {
        float sa = Sa[b * 256 + t];
        float ss = sa * sa;
        #pragma unroll
        for (int off = 1; off < 16; off <<= 1) ss += __shfl_xor(ss, off);
        ss = ss < 1e-12f ? 1e-12f : ss;
        float vv = sa / sqrtf(ss);
        if (use2) {
            float sb = Sb[b * 256 + t];
            float s2v = sb * sb;
            #pragma unroll
            for (int off = 1; off < 16; off <<= 1) s2v += __shfl_xor(s2v, off);
            s2v = s2v < 1e-12f ? 1e-12f : s2v;
            vv += sb / sqrtf(s2v);
        }
        vs[(t >> 4) * 17 + (t & 15)] = vv;
    }
    // prefetch all 4 positions (8 outstanding 16B loads) while v finishes
    const u16* xbase = X + ((b << 12) + chunk * 64 + nl) * 256 + c * 16;
    uint4 pa[8];
    #pragma unroll
    for (int r = 0; r < 4; ++r) {
        pa[2 * r]     = ((const uint4*)(xbase + r * 4096))[0];
        pa[2 * r + 1] = ((const uint4*)(xbase + r * 4096))[1];
    }
    __syncthreads();
    // register-cache this thread's vsum row (conflict-free: stride 17)
    float vr[16];
    #pragma unroll
    for (int d = 0; d < 16; ++d) vr[d] = vs[c * 17 + d];

    float acc[16];
    #pragma unroll
    for (int d = 0; d < 16; ++d) acc[d] = 0.f;

    #pragma unroll
    for (int r = 0; r < 4; ++r) {
        u32 us[8];
        __builtin_memcpy(us, &pa[2 * r], 32);
        float xf[16];
        #pragma unroll
        for (int j = 0; j < 8; ++j) { xf[2*j] = blo(us[j]); xf[2*j+1] = bhi(us[j]); }
        float bvv = 0.f;
        #pragma unroll
        for (int d = 0; d < 16; ++d) bvv += xf[d] * vr[d];
        float e = __expf(bvv);                    // |b| small: stable w/o max
        float sm = e;
        #pragma unroll
        for (int off = 1; off < 16; off <<= 1) sm += __shfl_xor(sm, off);
        float w = e / sm;
        #pragma unroll
        for (int d = 0; d < 16; ++d) acc[d] += w * xf[d];
    }
    // reduce the wave's 4 nl groups (lanes +-16, +-32) -> lanes 0..15
    #pragma unroll
    for (int d = 0; d < 16; ++d) {
        acc[d] += __shfl_xor(acc[d], 16);
        acc[d] += __shfl_xor(acc[d], 32);
    }
    if (lane < 16) {
        #pragma unroll
        for (int d = 0; d < 16; ++d) red[wid * 272 + lane * 17 + d] = acc[d];
    }
    __syncthreads();
    {
        int c2 = t >> 4, d2 = t & 15;
        float tot = red[c2 * 17 + d2]       + red[272 + c2 * 17 + d2]
                  + red[544 + c2 * 17 + d2] + red[816 + c2 * 17 + d2];
        atomicAdd(&Sout[b * 256 + t], tot);
    }
}

// ---------------------------------------------------------------------------
// final: v = l2_normalize(s3), broadcast to (B,64,64,256) fp32.
// v hoisted to a register (loop-invariant per thread).
// ---------------------------------------------------------------------------
__launch_bounds__(256, 4)
__global__ void k_bcast(const float* __restrict__ S, float* __restrict__ Out) {
    __shared__ float vls[256];
    int t = threadIdx.x, bx = blockIdx.x, b = blockIdx.y;
    float s = S[b * 256 + t];
    float ss = s * s;
    #pragma unroll
    for (int off = 1; off < 16; off <<= 1) ss += __shfl_xor(ss, off);
    ss = ss < 1e-12f ? 1e-12f : ss;
    vls[t] = s / sqrtf(ss);
    __syncthreads();
    float4 myv = ((const float4*)vls)[t & 63];    // (j*256+t)&63 == t&63
    float4* o = (float4*)Out + (long)b * 262144 + bx * 4096;
    #pragma unroll
    for (int j = 0; j < 16; ++j) o[j * 256 + t] = myv;
}

// ---------------------------------------------------------------------------
extern "C" void kernel_launch(void* const* d_in, const int* in_sizes, int n_in,
                              void* d_out, int out_size, void* d_ws, size_t ws_size,
                              hipStream_t stream) {
    const float* in   = (const float*)d_in[0];   // (16,64,64,128)
    const float* wk   = (const float*)d_in[1];   // (3,3,128,256)
    const float* bias = (const float*)d_in[2];   // (256,)
    float* out = (float*)d_out;
    char* ws = (char*)d_ws;

    // workspace layout (bytes) — pad tensor eliminated
    const size_t OFF_BF  = 0;                    // 294912*2      =    589,824
    const size_t OFF_X   = 589824;               // 16*4096*256*2 = 33,554,432
    const size_t OFF_ST  = 34144256;             // s0,s2,s3      = 3*16,384
    const size_t NEEDED  = OFF_ST + 3 * 16384;
    if (ws_size < NEEDED) return;                // fail loudly (validation error)

    u16* BF  = (u16*)(ws + OFF_BF);
    u16* X   = (u16*)(ws + OFF_X);
    float* s0 = (float*)(ws + OFF_ST);
    float* s2 = s0 + 4096;
    float* s3 = s2 + 4096;

    k_prep <<<1200, 256, 0, stream>>>(wk, BF, s0);
    k_conv <<<1024, 256, 0, stream>>>(in, BF, bias, X, s0);
    k_pass <<<dim3(64, 16), 256, 0, stream>>>(X, s0, s0, s2, 0);
    k_pass <<<dim3(64, 16), 256, 0, stream>>>(X, s0, s2, s3, 1);
    k_bcast<<<dim3(64, 16), 256, 0, stream>>>(s3, out);
}

// Round 3
// 166.793 us; speedup vs baseline: 1.0905x; 1.0905x over previous
//
#include <hip/hip_runtime.h>
#include <hip/hip_bf16.h>

typedef unsigned short u16;
typedef unsigned int   u32;

typedef __bf16 bf16x8 __attribute__((ext_vector_type(8)));
typedef float  f32x4  __attribute__((ext_vector_type(4)));

__device__ __forceinline__ u16 f2b(float f) {
    __hip_bfloat16 h = __float2bfloat16(f);
    u16 u; __builtin_memcpy(&u, &h, 2); return u;
}
__device__ __forceinline__ float blo(u32 u) { return __uint_as_float(u << 16); }
__device__ __forceinline__ float bhi(u32 u) { return __uint_as_float(u & 0xffff0000u); }

// ---------------------------------------------------------------------------
// prep (unchanged):
//  section B (blocks [0,1152)):    weights -> MFMA B-fragment order
//       BF[(((p*4+g)*4+q)*256 + n)*8 + j] = bf16(w[(p*128+g*32+q*8+j)*256+n])
//  section C (blocks [1152,1200)): zero s0,s2,s3 (12288 floats)
// ---------------------------------------------------------------------------
__global__ void k_prep(const float* __restrict__ wk,
                       u16* __restrict__ BF, float* __restrict__ stats) {
    int bx = blockIdx.x, tid = threadIdx.x;
    if (bx < 1152) {
        int t = bx * 256 + tid;                   // 294912 total, exact
        int j  = t & 7;
        int n  = (t >> 3) & 255;
        int q  = (t >> 11) & 3;
        int kk = (t >> 13) & 3;
        int p  = t >> 15;
        BF[t] = f2b(wk[(p * 128 + kk * 32 + q * 8 + j) * 256 + n]);
    } else {
        stats[(bx - 1152) * 256 + tid] = 0.f;     // 12288 floats
    }
}

// ---------------------------------------------------------------------------
// conv: implicit GEMM. Block = one image row: M=64, N=256, K=1152.
// R15 = R14 structure with the K-loop chain bug fixed (R14 left placeholder
// COMP/LOAD lines in, double-counting two K-steps and corrupting step 0;
// absmax 3.3e-2). Chain now: prologue loads (0,0),(0,1) in flight across
// the barrier -> COMP(0,0,0) -> clean 35-step ping-pong.
// Structure (theory from R13 post-mortem: occupancy must come from a
// smaller wave tile, not allocator pressure — (256,3) on the 64x64 tile
// spilled, WRITE_SIZE 33.8->72.7MB):
//  - 8 waves (512 thr), wave tile 32x64: wr=wid>>2 (M half), wc=wid&3
//    (n-group). acc = 2x4 f32x4 = 32 regs; B ping-pong 4-frag = 32 regs.
//    Natural demand ~105 unified regs -> __launch_bounds__(512,4) = 128
//    budget, no squeeze. 4 waves/SIMD resident (R12 had 2).
//  - Single full-K stage: all 128 channels in LDS (3x66x16 chunks =
//    50688 B; 2 blocks/CU = 101 KB). ONE barrier, then 36 barrier-free
//    MFMA steps. Two-phase stage: issue all 14 dwordx4 loads, then
//    cvt+ds_write, before accumulators are live.
//  - Per-block LDS read traffic unchanged vs R12 (576 x b128).
// Swizzled LDS layout [pr][wp][cs ^ (wp&7)], cs 0..15 (4-bit chunk id,
// XOR on low 3 bits). Epilogue: +bias, relu, store x bf16, atomic s0.
// ---------------------------------------------------------------------------
__launch_bounds__(512, 4)
__global__ void k_conv(const float* __restrict__ in, const u16* __restrict__ BF,
                       const float* __restrict__ bias,
                       u16* __restrict__ X, float* __restrict__ s0) {
    __shared__ u16 ldsA[25344];                   // 3*66*16 chunks = 50688 B
    const int t = threadIdx.x;
    const int lane = t & 63, wid = t >> 6;        // 8 waves
    const int q = lane >> 4, l15 = lane & 15;
    const int wr = wid >> 2;                      // M half (0: rows 0-31, 1: 32-63)
    const int wc = wid & 3;                       // n-group (64 cols each)
    const int bb = blockIdx.x >> 6;               // batch
    const int h  = blockIdx.x & 63;               // output row
    const int wn0 = wc << 6;

    // full-K stage: 3168 slots (3 rows x 66 wp x 16 cs-chunks), 512 threads,
    // 7 iters (last partial: 96). Two-phase: issue-all then cvt+write.
    // Branchless loads: OOB -> clamped valid address, result zeroed.
#define STAGE_ALL() { \
    float4 fa[7], fb[7]; float zf[7]; \
    _Pragma("unroll") for (int i = 0; i < 7; ++i) { \
        int slot = i * 512 + t; \
        int ok = (i < 6) | (t < 96); \
        int pr = slot / 1056; int rem = slot - pr * 1056; \
        int wp = rem >> 4, cs = rem & 15; \
        int gc = cs ^ (wp & 7); \
        int y = h + pr - 1, x = wp - 1; \
        int inb = ok & ((((unsigned)y < 64u) & ((unsigned)x < 64u)) ? 1 : 0); \
        int ys = inb ? y : 0, xs = inb ? x : 0; \
        const float4* s4 = (const float4*)(in + \
            (((bb * 64 + ys) * 64 + xs) * 128 + gc * 8)); \
        fa[i] = s4[0]; fb[i] = s4[1]; \
        zf[i] = inb ? 1.f : 0.f; \
    } \
    _Pragma("unroll") for (int i = 0; i < 7; ++i) { \
        if (i < 6 || t < 96) { \
            int slot = i * 512 + t; \
            u16 ov[8]; \
            ov[0]=f2b(fa[i].x*zf[i]); ov[1]=f2b(fa[i].y*zf[i]); \
            ov[2]=f2b(fa[i].z*zf[i]); ov[3]=f2b(fa[i].w*zf[i]); \
            ov[4]=f2b(fb[i].x*zf[i]); ov[5]=f2b(fb[i].y*zf[i]); \
            ov[6]=f2b(fb[i].z*zf[i]); ov[7]=f2b(fb[i].w*zf[i]); \
            uint4 wv; __builtin_memcpy(&wv, ov, 16); \
            *(uint4*)((char*)ldsA + slot * 16) = wv; \
        } \
    } }

    // load one 4-fragment B group: (tap P = dh*3+dw, k-group G 0..3)
#define LOADB4(B, P, G) { \
    _Pragma("unroll") for (int ni = 0; ni < 4; ++ni) \
        B[ni] = *(const bf16x8*)(BFl + (P) * 32768 + (G) * 8192 + ni * 128); }

    // one 8-MFMA compute step for (DH, DW, G) using B group B
#define COMP4(B, DH, DW, G) { \
    bf16x8 af[2]; \
    _Pragma("unroll") for (int mi = 0; mi < 2; ++mi) { \
        int wp = wr * 32 + mi * 16 + l15 + (DW); \
        int swz = ((G) * 4 + q) ^ (wp & 7); \
        af[mi] = *(const bf16x8*)((const char*)ldsA + \
            (((DH) * 1056 + wp * 16 + swz) << 4)); \
    } \
    _Pragma("unroll") for (int mi = 0; mi < 2; ++mi) \
    _Pragma("unroll") for (int ni = 0; ni < 4; ++ni) \
        acc[mi][ni] = __builtin_amdgcn_mfma_f32_16x16x32_bf16( \
            af[mi], B[ni], acc[mi][ni], 0, 0, 0); }

    // 35-step barrier-free ping-pong chain, (P,G) G-inner, one-behind pairing
#define CHAIN() { \
    LOADB4(B0, 0, 2); COMP4(B1, 0, 0, 1); \
    LOADB4(B1, 0, 3); COMP4(B0, 0, 0, 2); \
    LOADB4(B0, 1, 0); COMP4(B1, 0, 0, 3); \
    LOADB4(B1, 1, 1); COMP4(B0, 0, 1, 0); \
    LOADB4(B0, 1, 2); COMP4(B1, 0, 1, 1); \
    LOADB4(B1, 1, 3); COMP4(B0, 0, 1, 2); \
    LOADB4(B0, 2, 0); COMP4(B1, 0, 1, 3); \
    LOADB4(B1, 2, 1); COMP4(B0, 0, 2, 0); \
    LOADB4(B0, 2, 2); COMP4(B1, 0, 2, 1); \
    LOADB4(B1, 2, 3); COMP4(B0, 0, 2, 2); \
    LOADB4(B0, 3, 0); COMP4(B1, 0, 2, 3); \
    LOADB4(B1, 3, 1); COMP4(B0, 1, 0, 0); \
    LOADB4(B0, 3, 2); COMP4(B1, 1, 0, 1); \
    LOADB4(B1, 3, 3); COMP4(B0, 1, 0, 2); \
    LOADB4(B0, 4, 0); COMP4(B1, 1, 0, 3); \
    LOADB4(B1, 4, 1); COMP4(B0, 1, 1, 0); \
    LOADB4(B0, 4, 2); COMP4(B1, 1, 1, 1); \
    LOADB4(B1, 4, 3); COMP4(B0, 1, 1, 2); \
    LOADB4(B0, 5, 0); COMP4(B1, 1, 1, 3); \
    LOADB4(B1, 5, 1); COMP4(B0, 1, 2, 0); \
    LOADB4(B0, 5, 2); COMP4(B1, 1, 2, 1); \
    LOADB4(B1, 5, 3); COMP4(B0, 1, 2, 2); \
    LOADB4(B0, 6, 0); COMP4(B1, 1, 2, 3); \
    LOADB4(B1, 6, 1); COMP4(B0, 2, 0, 0); \
    LOADB4(B0, 6, 2); COMP4(B1, 2, 0, 1); \
    LOADB4(B1, 6, 3); COMP4(B0, 2, 0, 2); \
    LOADB4(B0, 7, 0); COMP4(B1, 2, 0, 3); \
    LOADB4(B1, 7, 1); COMP4(B0, 2, 1, 0); \
    LOADB4(B0, 7, 2); COMP4(B1, 2, 1, 1); \
    LOADB4(B1, 7, 3); COMP4(B0, 2, 1, 2); \
    LOADB4(B0, 8, 0); COMP4(B1, 2, 1, 3); \
    LOADB4(B1, 8, 1); COMP4(B0, 2, 2, 0); \
    LOADB4(B0, 8, 2); COMP4(B1, 2, 2, 1); \
    LOADB4(B1, 8, 3); COMP4(B0, 2, 2, 2); \
                      COMP4(B1, 2, 2, 3); }

    const u16* BFl = BF + (q * 2048 + (wn0 + l15) * 8);

    STAGE_ALL();

    f32x4 zero = {0.f, 0.f, 0.f, 0.f};
    f32x4 acc[2][4];
    #pragma unroll
    for (int mi = 0; mi < 2; ++mi)
        #pragma unroll
        for (int ni = 0; ni < 4; ++ni) acc[mi][ni] = zero;

    bf16x8 B0[4], B1[4];
    LOADB4(B0, 0, 0);                             // in flight across barrier
    LOADB4(B1, 0, 1);
    __syncthreads();

    COMP4(B0, 0, 0, 0);
    CHAIN();

    // epilogue: bias + relu, store bf16 x, column sums -> s0
    float bv[4];
    #pragma unroll
    for (int ni = 0; ni < 4; ++ni) bv[ni] = bias[wn0 + ni * 16 + l15];
    float colsum[4] = {0.f, 0.f, 0.f, 0.f};
    u16* xrow = X + (((bb << 12) + (h << 6) + wr * 32 + q * 4) * 256) + wn0 + l15;
    #pragma unroll
    for (int mi = 0; mi < 2; ++mi) {
        #pragma unroll
        for (int rr = 0; rr < 4; ++rr) {
            u16* xp = xrow + (mi * 16 + rr) * 256;
            #pragma unroll
            for (int ni = 0; ni < 4; ++ni) {
                float v = acc[mi][ni][rr] + bv[ni];
                v = v > 0.f ? v : 0.f;
                xp[ni * 16] = f2b(v);
                colsum[ni] += v;
            }
        }
    }
    #pragma unroll
    for (int ni = 0; ni < 4; ++ni) {
        float c = colsum[ni];
        c += __shfl_xor(c, 16);
        c += __shfl_xor(c, 32);
        if (lane < 16) atomicAdd(&s0[bb * 256 + wn0 + ni * 16 + l15], c);
    }
#undef STAGE_ALL
#undef LOADB4
#undef COMP4
#undef CHAIN
}

// ---------------------------------------------------------------------------
// routing pass v3 (unchanged, R9/R11-measured best): 64 positions/block,
// grid 64x16. vsum register-cached -> ONE dot per position. Stride-17 LDS,
// 8 outstanding X-loads, shfl n-reduce. b-logits bounded -> no max pass.
// ---------------------------------------------------------------------------
__launch_bounds__(256, 4)
__global__ void k_pass(const u16* __restrict__ X, const float* __restrict__ Sa,
                       const float* __restrict__ Sb, float* __restrict__ Sout,
                       int use2) {
    __shared__ float vs[272];                     // [cap*17 + d]
    __shared__ float red[4 * 272];                // [wave][c*17 + d]
    const int t = threadIdx.x, b = blockIdx.y, chunk = blockIdx.x;
    const int c = t & 15, nl = t >> 4;
    const int lane = t & 63, wid = t >> 6;
    {
        float sa = Sa[b * 256 + t];
        float ss = sa * sa;
        #pragma unroll
        for (int off = 1; off < 16; off <<= 1) ss += __shfl_xor(ss, off);
        ss = ss < 1e-12f ? 1e-12f : ss;
        float vv = sa / sqrtf(ss);
        if (use2) {
            float sb = Sb[b * 256 + t];
            float s2v = sb * sb;
            #pragma unroll
            for (int off = 1; off < 16; off <<= 1) s2v += __shfl_xor(s2v, off);
            s2v = s2v < 1e-12f ? 1e-12f : s2v;
            vv += sb / sqrtf(s2v);
        }
        vs[(t >> 4) * 17 + (t & 15)] = vv;
    }
    // prefetch all 4 positions (8 outstanding 16B loads) while v finishes
    const u16* xbase = X + ((b << 12) + chunk * 64 + nl) * 256 + c * 16;
    uint4 pa[8];
    #pragma unroll
    for (int r = 0; r < 4; ++r) {
        pa[2 * r]     = ((const uint4*)(xbase + r * 4096))[0];
        pa[2 * r + 1] = ((const uint4*)(xbase + r * 4096))[1];
    }
    __syncthreads();
    // register-cache this thread's vsum row (conflict-free: stride 17)
    float vr[16];
    #pragma unroll
    for (int d = 0; d < 16; ++d) vr[d] = vs[c * 17 + d];

    float acc[16];
    #pragma unroll
    for (int d = 0; d < 16; ++d) acc[d] = 0.f;

    #pragma unroll
    for (int r = 0; r < 4; ++r) {
        u32 us[8];
        __builtin_memcpy(us, &pa[2 * r], 32);
        float xf[16];
        #pragma unroll
        for (int j = 0; j < 8; ++j) { xf[2*j] = blo(us[j]); xf[2*j+1] = bhi(us[j]); }
        float bvv = 0.f;
        #pragma unroll
        for (int d = 0; d < 16; ++d) bvv += xf[d] * vr[d];
        float e = __expf(bvv);                    // |b| small: stable w/o max
        float sm = e;
        #pragma unroll
        for (int off = 1; off < 16; off <<= 1) sm += __shfl_xor(sm, off);
        float w = e / sm;
        #pragma unroll
        for (int d = 0; d < 16; ++d) acc[d] += w * xf[d];
    }
    // reduce the wave's 4 nl groups (lanes +-16, +-32) -> lanes 0..15
    #pragma unroll
    for (int d = 0; d < 16; ++d) {
        acc[d] += __shfl_xor(acc[d], 16);
        acc[d] += __shfl_xor(acc[d], 32);
    }
    if (lane < 16) {
        #pragma unroll
        for (int d = 0; d < 16; ++d) red[wid * 272 + lane * 17 + d] = acc[d];
    }
    __syncthreads();
    {
        int c2 = t >> 4, d2 = t & 15;
        float tot = red[c2 * 17 + d2]       + red[272 + c2 * 17 + d2]
                  + red[544 + c2 * 17 + d2] + red[816 + c2 * 17 + d2];
        atomicAdd(&Sout[b * 256 + t], tot);
    }
}

// ---------------------------------------------------------------------------
// final: v = l2_normalize(s3), broadcast to (B,64,64,256) fp32. (unchanged)
// ---------------------------------------------------------------------------
__launch_bounds__(256, 4)
__global__ void k_bcast(const float* __restrict__ S, float* __restrict__ Out) {
    __shared__ float vls[256];
    int t = threadIdx.x, bx = blockIdx.x, b = blockIdx.y;
    float s = S[b * 256 + t];
    float ss = s * s;
    #pragma unroll
    for (int off = 1; off < 16; off <<= 1) ss += __shfl_xor(ss, off);
    ss = ss < 1e-12f ? 1e-12f : ss;
    vls[t] = s / sqrtf(ss);
    __syncthreads();
    float4 myv = ((const float4*)vls)[t & 63];    // (j*256+t)&63 == t&63
    float4* o = (float4*)Out + (long)b * 262144 + bx * 4096;
    #pragma unroll
    for (int j = 0; j < 16; ++j) o[j * 256 + t] = myv;
}

// ---------------------------------------------------------------------------
extern "C" void kernel_launch(void* const* d_in, const int* in_sizes, int n_in,
                              void* d_out, int out_size, void* d_ws, size_t ws_size,
                              hipStream_t stream) {
    const float* in   = (const float*)d_in[0];   // (16,64,64,128)
    const float* wk   = (const float*)d_in[1];   // (3,3,128,256)
    const float* bias = (const float*)d_in[2];   // (256,)
    float* out = (float*)d_out;
    char* ws = (char*)d_ws;

    // workspace layout (bytes)
    const size_t OFF_BF  = 0;                    // 294912*2      =    589,824
    const size_t OFF_X   = 589824;               // 16*4096*256*2 = 33,554,432
    const size_t OFF_ST  = 34144256;             // s0,s2,s3      = 3*16,384
    const size_t NEEDED  = OFF_ST + 3 * 16384;
    if (ws_size < NEEDED) return;                // fail loudly (validation error)

    u16* BF  = (u16*)(ws + OFF_BF);
    u16* X   = (u16*)(ws + OFF_X);
    float* s0 = (float*)(ws + OFF_ST);
    float* s2 = s0 + 4096;
    float* s3 = s2 + 4096;

    k_prep <<<1200, 256, 0, stream>>>(wk, BF, s0);
    k_conv <<<1024, 512, 0, stream>>>(in, BF, bias, X, s0);
    k_pass <<<dim3(64, 16), 256, 0, stream>>>(X, s0, s0, s2, 0);
    k_pass <<<dim3(64, 16), 256, 0, stream>>>(X, s0, s2, s3, 1);
    k_bcast<<<dim3(64, 16), 256, 0, stream>>>(s3, out);
}

// Round 4
// 166.023 us; speedup vs baseline: 1.0956x; 1.0046x over previous
//
#include <hip/hip_runtime.h>
#include <hip/hip_bf16.h>

typedef unsigned short u16;
typedef unsigned int   u32;

typedef __bf16 bf16x8 __attribute__((ext_vector_type(8)));
typedef float  f32x4  __attribute__((ext_vector_type(4)));

__device__ __forceinline__ u16 f2b(float f) {
    __hip_bfloat16 h = __float2bfloat16(f);
    u16 u; __builtin_memcpy(&u, &h, 2); return u;
}
__device__ __forceinline__ float blo(u32 u) { return __uint_as_float(u << 16); }
__device__ __forceinline__ float bhi(u32 u) { return __uint_as_float(u & 0xffff0000u); }

// ---------------------------------------------------------------------------
// prep (unchanged):
//  section B (blocks [0,1152)):    weights -> MFMA B-fragment order
//       BF[(((p*4+g)*4+q)*256 + n)*8 + j] = bf16(w[(p*128+g*32+q*8+j)*256+n])
//  section C (blocks [1152,1200)): zero s0,s2,s3 (12288 floats)
// ---------------------------------------------------------------------------
__global__ void k_prep(const float* __restrict__ wk,
                       u16* __restrict__ BF, float* __restrict__ stats) {
    int bx = blockIdx.x, tid = threadIdx.x;
    if (bx < 1152) {
        int t = bx * 256 + tid;                   // 294912 total, exact
        int j  = t & 7;
        int n  = (t >> 3) & 255;
        int q  = (t >> 11) & 3;
        int kk = (t >> 13) & 3;
        int p  = t >> 15;
        BF[t] = f2b(wk[(p * 128 + kk * 32 + q * 8 + j) * 256 + n]);
    } else {
        stats[(bx - 1152) * 256 + tid] = 0.f;     // 12288 floats
    }
}

// ---------------------------------------------------------------------------
// conv: implicit GEMM. Block = one image row: M=64, N=256, K=1152.
// R16 post-mortems:
//  R13: (256,3) on 64x64 tile -> spill (WRITE 33.8->72.7MB). Occupancy must
//       come from smaller tiles, not allocator squeeze.
//  R15: 8-wave 32x64 tile doubled occupancy (38.9%) but k_conv 60->67us:
//       (a) 4-frag ping-pong = 8-MFMA (~40cyc) cover per step, stalls on
//       vmcnt every step; (b) merged 16-chunk LDS row (256B stride, 3-bit
//       XOR) introduced 2.36M bank conflicts (R12 layout measured 0).
// R16 = R15 occupancy + R12's proven per-step cover and LDS geometry:
//  - 8 waves (512 thr), wave tile 32x64 (wr=wid>>2 M-half, wc=wid&3).
//    acc 2x4 f32x4 = 32 regs.
//  - B ping-pong at 8-fragment granularity: B0[8]+B1[8] = 64 regs; step =
//    LOADB8 (8 dwordx4, L1-hit: B is wr- and block-invariant) + COMP8
//    (16 MFMA ~100cyc incl ds_reads) -> one-behind cover ~L1 latency,
//    x4 waves/SIMD TLP on top. Total demand ~120 regs < 128 @ (512,4).
//  - LDS = TWO R12-layout sections [S][3][66][8] chunks (row stride 128B,
//    swz = (kk*4+q)^(wp&7)) = 50688B, 2 blocks/CU. Single barrier.
//  - Stage: all 14 dwordx4 issued first, then cvt+ds_write (two-phase).
// Epilogue: +bias, relu, store x bf16, atomic-accumulate s0.
// ---------------------------------------------------------------------------
__launch_bounds__(512, 4)
__global__ void k_conv(const float* __restrict__ in, const u16* __restrict__ BF,
                       const float* __restrict__ bias,
                       u16* __restrict__ X, float* __restrict__ s0) {
    __shared__ u16 ldsA[25344];                   // 2 sections x 1584 chunks x 16B
    const int t = threadIdx.x;
    const int lane = t & 63, wid = t >> 6;        // 8 waves
    const int q = lane >> 4, l15 = lane & 15;
    const int wr = wid >> 2;                      // M half (0: w 0-31, 1: w 32-63)
    const int wc = wid & 3;                       // n-group (64 cols each)
    const int bb = blockIdx.x >> 6;               // batch
    const int h  = blockIdx.x & 63;               // output row
    const int wn0 = wc << 6;

    // full-K stage: 3168 slots = 2 sections x (3 pr x 66 wp x 8 cs), 512 thr,
    // 7 iters (last partial: 96). slot -> [S][pr][wp][cs], gc = S*8+(cs^(wp&7)).
    // Two-phase: issue all loads, then cvt+write. Branchless borders.
#define STAGE_ALL() { \
    float4 fa[7], fb[7]; float zf[7]; \
    _Pragma("unroll") for (int i = 0; i < 7; ++i) { \
        int slot = i * 512 + t; \
        int ok = (i < 6) | (t < 96); \
        int S = slot / 1584; int r2 = slot - S * 1584; \
        int pr = r2 / 528; int rem = r2 - pr * 528; \
        int wp = rem >> 3, cs = rem & 7; \
        int gc = S * 8 + (cs ^ (wp & 7)); \
        int y = h + pr - 1, x = wp - 1; \
        int inb = ok & ((((unsigned)y < 64u) & ((unsigned)x < 64u)) ? 1 : 0); \
        int ys = inb ? y : 0, xs = inb ? x : 0; \
        const float4* s4 = (const float4*)(in + \
            (((bb * 64 + ys) * 64 + xs) * 128 + gc * 8)); \
        fa[i] = s4[0]; fb[i] = s4[1]; \
        zf[i] = inb ? 1.f : 0.f; \
    } \
    _Pragma("unroll") for (int i = 0; i < 7; ++i) { \
        if (i < 6 || t < 96) { \
            int slot = i * 512 + t; \
            u16 ov[8]; \
            ov[0]=f2b(fa[i].x*zf[i]); ov[1]=f2b(fa[i].y*zf[i]); \
            ov[2]=f2b(fa[i].z*zf[i]); ov[3]=f2b(fa[i].w*zf[i]); \
            ov[4]=f2b(fb[i].x*zf[i]); ov[5]=f2b(fb[i].y*zf[i]); \
            ov[6]=f2b(fb[i].z*zf[i]); ov[7]=f2b(fb[i].w*zf[i]); \
            uint4 wv; __builtin_memcpy(&wv, ov, 16); \
            *(uint4*)((char*)ldsA + slot * 16) = wv; \
        } \
    } }

    // load one 8-fragment B group: tap P, section S2 (k-groups S2*2, S2*2+1)
#define LOADB8(B, P, S2) { \
    _Pragma("unroll") for (int kk = 0; kk < 2; ++kk) \
    _Pragma("unroll") for (int ni = 0; ni < 4; ++ni) \
        B[kk * 4 + ni] = *(const bf16x8*)(BFl + (P) * 32768 + \
                                          ((S2) * 2 + kk) * 8192 + ni * 128); }

    // one 16-MFMA compute step for (DH, DW, section S2) using B group B
#define COMP8(B, DH, DW, S2) { \
    _Pragma("unroll") for (int kk = 0; kk < 2; ++kk) { \
        bf16x8 af[2]; \
        _Pragma("unroll") for (int mi = 0; mi < 2; ++mi) { \
            int wp = wr * 32 + mi * 16 + l15 + (DW); \
            int swz = (kk * 4 + q) ^ (wp & 7); \
            af[mi] = *(const bf16x8*)((const char*)ldsA + \
                (((S2) * 1584 + (DH) * 528 + wp * 8 + swz) << 4)); \
        } \
        _Pragma("unroll") for (int mi = 0; mi < 2; ++mi) \
        _Pragma("unroll") for (int ni = 0; ni < 4; ++ni) \
            acc[mi][ni] = __builtin_amdgcn_mfma_f32_16x16x32_bf16( \
                af[mi], B[kk * 4 + ni], acc[mi][ni], 0, 0, 0); } }

    const u16* BFl = BF + (q * 2048 + (wn0 + l15) * 8);

    STAGE_ALL();

    f32x4 zero = {0.f, 0.f, 0.f, 0.f};
    f32x4 acc[2][4];
    #pragma unroll
    for (int mi = 0; mi < 2; ++mi)
        #pragma unroll
        for (int ni = 0; ni < 4; ++ni) acc[mi][ni] = zero;

    bf16x8 B0[8], B1[8];
    LOADB8(B0, 0, 0);                             // in flight across barrier
    LOADB8(B1, 0, 1);
    __syncthreads();

    // 18-step barrier-free ping-pong, one-behind pairing. P=DH*3+DW.
    COMP8(B0, 0, 0, 0);
    LOADB8(B0, 1, 0); COMP8(B1, 0, 0, 1);
    LOADB8(B1, 1, 1); COMP8(B0, 0, 1, 0);
    LOADB8(B0, 2, 0); COMP8(B1, 0, 1, 1);
    LOADB8(B1, 2, 1); COMP8(B0, 0, 2, 0);
    LOADB8(B0, 3, 0); COMP8(B1, 0, 2, 1);
    LOADB8(B1, 3, 1); COMP8(B0, 1, 0, 0);
    LOADB8(B0, 4, 0); COMP8(B1, 1, 0, 1);
    LOADB8(B1, 4, 1); COMP8(B0, 1, 1, 0);
    LOADB8(B0, 5, 0); COMP8(B1, 1, 1, 1);
    LOADB8(B1, 5, 1); COMP8(B0, 1, 2, 0);
    LOADB8(B0, 6, 0); COMP8(B1, 1, 2, 1);
    LOADB8(B1, 6, 1); COMP8(B0, 2, 0, 0);
    LOADB8(B0, 7, 0); COMP8(B1, 2, 0, 1);
    LOADB8(B1, 7, 1); COMP8(B0, 2, 1, 0);
    LOADB8(B0, 8, 0); COMP8(B1, 2, 1, 1);
    LOADB8(B1, 8, 1); COMP8(B0, 2, 2, 0);
                      COMP8(B1, 2, 2, 1);

    // epilogue: bias + relu, store bf16 x, column sums -> s0
    float bv[4];
    #pragma unroll
    for (int ni = 0; ni < 4; ++ni) bv[ni] = bias[wn0 + ni * 16 + l15];
    float colsum[4] = {0.f, 0.f, 0.f, 0.f};
    u16* xrow = X + (((bb << 12) + (h << 6) + wr * 32 + q * 4) * 256) + wn0 + l15;
    #pragma unroll
    for (int mi = 0; mi < 2; ++mi) {
        #pragma unroll
        for (int rr = 0; rr < 4; ++rr) {
            u16* xp = xrow + (mi * 16 + rr) * 256;
            #pragma unroll
            for (int ni = 0; ni < 4; ++ni) {
                float v = acc[mi][ni][rr] + bv[ni];
                v = v > 0.f ? v : 0.f;
                xp[ni * 16] = f2b(v);
                colsum[ni] += v;
            }
        }
    }
    #pragma unroll
    for (int ni = 0; ni < 4; ++ni) {
        float c = colsum[ni];
        c += __shfl_xor(c, 16);
        c += __shfl_xor(c, 32);
        if (lane < 16) atomicAdd(&s0[bb * 256 + wn0 + ni * 16 + l15], c);
    }
#undef STAGE_ALL
#undef LOADB8
#undef COMP8
}

// ---------------------------------------------------------------------------
// routing pass v3 (unchanged, R9/R11-measured best): 64 positions/block,
// grid 64x16. vsum register-cached -> ONE dot per position. Stride-17 LDS,
// 8 outstanding X-loads, shfl n-reduce. b-logits bounded -> no max pass.
// ---------------------------------------------------------------------------
__launch_bounds__(256, 4)
__global__ void k_pass(const u16* __restrict__ X, const float* __restrict__ Sa,
                       const float* __restrict__ Sb, float* __restrict__ Sout,
                       int use2) {
    __shared__ float vs[272];                     // [cap*17 + d]
    __shared__ float red[4 * 272];                // [wave][c*17 + d]
    const int t = threadIdx.x, b = blockIdx.y, chunk = blockIdx.x;
    const int c = t & 15, nl = t >> 4;
    const int lane = t & 63, wid = t >> 6;
    {
        float sa = Sa[b * 256 + t];
        float ss = sa * sa;
        #pragma unroll
        for (int off = 1; off < 16; off <<= 1) ss += __shfl_xor(ss, off);
        ss = ss < 1e-12f ? 1e-12f : ss;
        float vv = sa / sqrtf(ss);
        if (use2) {
            float sb = Sb[b * 256 + t];
            float s2v = sb * sb;
            #pragma unroll
            for (int off = 1; off < 16; off <<= 1) s2v += __shfl_xor(s2v, off);
            s2v = s2v < 1e-12f ? 1e-12f : s2v;
            vv += sb / sqrtf(s2v);
        }
        vs[(t >> 4) * 17 + (t & 15)] = vv;
    }
    // prefetch all 4 positions (8 outstanding 16B loads) while v finishes
    const u16* xbase = X + ((b << 12) + chunk * 64 + nl) * 256 + c * 16;
    uint4 pa[8];
    #pragma unroll
    for (int r = 0; r < 4; ++r) {
        pa[2 * r]     = ((const uint4*)(xbase + r * 4096))[0];
        pa[2 * r + 1] = ((const uint4*)(xbase + r * 4096))[1];
    }
    __syncthreads();
    // register-cache this thread's vsum row (conflict-free: stride 17)
    float vr[16];
    #pragma unroll
    for (int d = 0; d < 16; ++d) vr[d] = vs[c * 17 + d];

    float acc[16];
    #pragma unroll
    for (int d = 0; d < 16; ++d) acc[d] = 0.f;

    #pragma unroll
    for (int r = 0; r < 4; ++r) {
        u32 us[8];
        __builtin_memcpy(us, &pa[2 * r], 32);
        float xf[16];
        #pragma unroll
        for (int j = 0; j < 8; ++j) { xf[2*j] = blo(us[j]); xf[2*j+1] = bhi(us[j]); }
        float bvv = 0.f;
        #pragma unroll
        for (int d = 0; d < 16; ++d) bvv += xf[d] * vr[d];
        float e = __expf(bvv);                    // |b| small: stable w/o max
        float sm = e;
        #pragma unroll
        for (int off = 1; off < 16; off <<= 1) sm += __shfl_xor(sm, off);
        float w = e / sm;
        #pragma unroll
        for (int d = 0; d < 16; ++d) acc[d] += w * xf[d];
    }
    // reduce the wave's 4 nl groups (lanes +-16, +-32) -> lanes 0..15
    #pragma unroll
    for (int d = 0; d < 16; ++d) {
        acc[d] += __shfl_xor(acc[d], 16);
        acc[d] += __shfl_xor(acc[d], 32);
    }
    if (lane < 16) {
        #pragma unroll
        for (int d = 0; d < 16; ++d) red[wid * 272 + lane * 17 + d] = acc[d];
    }
    __syncthreads();
    {
        int c2 = t >> 4, d2 = t & 15;
        float tot = red[c2 * 17 + d2]       + red[272 + c2 * 17 + d2]
                  + red[544 + c2 * 17 + d2] + red[816 + c2 * 17 + d2];
        atomicAdd(&Sout[b * 256 + t], tot);
    }
}

// ---------------------------------------------------------------------------
// final: v = l2_normalize(s3), broadcast to (B,64,64,256) fp32. (unchanged)
// ---------------------------------------------------------------------------
__launch_bounds__(256, 4)
__global__ void k_bcast(const float* __restrict__ S, float* __restrict__ Out) {
    __shared__ float vls[256];
    int t = threadIdx.x, bx = blockIdx.x, b = blockIdx.y;
    float s = S[b * 256 + t];
    float ss = s * s;
    #pragma unroll
    for (int off = 1; off < 16; off <<= 1) ss += __shfl_xor(ss, off);
    ss = ss < 1e-12f ? 1e-12f : ss;
    vls[t] = s / sqrtf(ss);
    __syncthreads();
    float4 myv = ((const float4*)vls)[t & 63];    // (j*256+t)&63 == t&63
    float4* o = (float4*)Out + (long)b * 262144 + bx * 4096;
    #pragma unroll
    for (int j = 0; j < 16; ++j) o[j * 256 + t] = myv;
}

// ---------------------------------------------------------------------------
extern "C" void kernel_launch(void* const* d_in, const int* in_sizes, int n_in,
                              void* d_out, int out_size, void* d_ws, size_t ws_size,
                              hipStream_t stream) {
    const float* in   = (const float*)d_in[0];   // (16,64,64,128)
    const float* wk   = (const float*)d_in[1];   // (3,3,128,256)
    const float* bias = (const float*)d_in[2];   // (256,)
    float* out = (float*)d_out;
    char* ws = (char*)d_ws;

    // workspace layout (bytes)
    const size_t OFF_BF  = 0;                    // 294912*2      =    589,824
    const size_t OFF_X   = 589824;               // 16*4096*256*2 = 33,554,432
    const size_t OFF_ST  = 34144256;             // s0,s2,s3      = 3*16,384
    const size_t NEEDED  = OFF_ST + 3 * 16384;
    if (ws_size < NEEDED) return;                // fail loudly (validation error)

    u16* BF  = (u16*)(ws + OFF_BF);
    u16* X   = (u16*)(ws + OFF_X);
    float* s0 = (float*)(ws + OFF_ST);
    float* s2 = s0 + 4096;
    float* s3 = s2 + 4096;

    k_prep <<<1200, 256, 0, stream>>>(wk, BF, s0);
    k_conv <<<1024, 512, 0, stream>>>(in, BF, bias, X, s0);
    k_pass <<<dim3(64, 16), 256, 0, stream>>>(X, s0, s0, s2, 0);
    k_pass <<<dim3(64, 16), 256, 0, stream>>>(X, s0, s2, s3, 1);
    k_bcast<<<dim3(64, 16), 256, 0, stream>>>(s3, out);
}